// Round 9
// baseline (4669.253 us; speedup 1.0000x reference)
//
#include <hip/hip_runtime.h>
#include <cstdint>
#include <cstddef>

// ---------------------------------------------------------------------------
// SDHGNN round 9: persistent megakernel. Round 8 was dispatch-bound
// (~200 us across 38 launches). All 4 layers now run in ONE kernel of
// 512 blocks x 512 threads (2 blocks/CU guaranteed: 58880 B LDS < 80 KB,
// launch_bounds caps VGPR at 128), with a device-scope grid barrier.
// Stage math identical to round 8: split-bf16 3-term everywhere on the
// p-path, PV pure-bf16. 256-thread sub-kernels run as pairs per block;
// all pair type-boundaries are even so __syncthreads counts match.
// ---------------------------------------------------------------------------

#define NB 2
#define ND 128
#define NH 4
#define NN 2048
#define DN (ND*NN)
#define BDN (NB*DN)
#define QK_SCALE 0.17677669529663687f
#define IN_EPS 1e-3f
#define NBLK 512

typedef unsigned short u16;
typedef __attribute__((ext_vector_type(8))) short short8;
typedef __attribute__((ext_vector_type(4))) float f32x4;

__device__ __forceinline__ u16 f2bf(float f) {
    unsigned u = __float_as_uint(f);
    return (u16)((u + 0x7fffu + ((u >> 16) & 1u)) >> 16);
}
__device__ __forceinline__ float bf2f(u16 h) {
    return __uint_as_float(((unsigned)h) << 16);
}

// monotonic grid barrier: cnt accumulates arrivals, gen releases generation g
__device__ __forceinline__ void gbar(unsigned* cnt, unsigned* gen, int g) {
    __threadfence();
    __syncthreads();
    if (threadIdx.x == 0) {
        unsigned n = atomicAdd(cnt, 1u);
        if (n == (unsigned)NBLK * (unsigned)g - 1u) atomicAdd(gen, 1u);
        else { while (atomicAdd(gen, 0u) < (unsigned)g) __builtin_amdgcn_s_sleep(8); }
    }
    __syncthreads();
    __threadfence();
}

// ---------------------------------------------------------------------------
__global__ __launch_bounds__(64) void barinit_kernel(unsigned* cnt, unsigned* gen)
{
    if (threadIdx.x == 0) { *cnt = 0u; *gen = 0u; }
}

// ---------------------------------------------------------------------------
__global__ __launch_bounds__(256) void init_kernel(
    const float* __restrict__ x0in, const float* __restrict__ x1in,
    float* __restrict__ out, int* __restrict__ idx0, int* __restrict__ idx1)
{
    int tid = blockIdx.x * 256 + threadIdx.x;
    const float4* a = (const float4*)x0in;
    const float4* b = (const float4*)x1in;
    float4* o = (float4*)out;
    o[tid] = a[tid];
    o[BDN/4 + tid] = b[tid];
    if (tid < NB*NN) {
        int v = tid & (NN-1);
        idx0[tid] = v;
        idx1[tid] = v;
    }
}

// ---------------------------------------------------------------------------
__global__ __launch_bounds__(256) void wrepack2_kernel(
    const float* __restrict__ Wq, const float* __restrict__ Wk,
    const float* __restrict__ Wv, const float* __restrict__ Wm,
    const float* __restrict__ W1, const float* __restrict__ W2,
    const float* __restrict__ bq, const float* __restrict__ bk,
    const float* __restrict__ bv,
    u16* __restrict__ whi, u16* __restrict__ wlo,
    float* __restrict__ bqp, float* __restrict__ bkp, float* __restrict__ bvp)
{
    int e = blockIdx.x * 256 + threadIdx.x;
    if (e < 655360) {
        int l = e / 163840, r = e - l*163840;
        float v;
        if (r < 49152) {
            int m = r >> 14;
            int rr = r & 16383;
            int o = rr >> 7, c = rr & 127;
            int so = (o & 31)*4 + (o >> 5);
            const float* W = (m == 0) ? Wq : ((m == 1) ? Wk : Wv);
            v = W[l*16384 + so*128 + c];
        } else if (r < 65536) {
            int rr = r - 49152;
            int o = rr >> 7, c = rr & 127;
            int sc = (c & 31)*4 + (c >> 5);
            v = Wm[l*16384 + o*128 + sc];
        } else if (r < 131072) v = W1[l*65536 + r - 65536];
        else                   v = W2[l*32768 + r - 131072];
        u16 hb = f2bf(v);
        whi[e] = hb;
        wlo[e] = f2bf(v - bf2f(hb));
    } else if (e < 656896) {
        int eb = e - 655360;
        int l = eb / 384, rr = eb % 384;
        int which = rr >> 7, o = rr & 127;
        int so = (o & 31)*4 + (o >> 5);
        float v = (which == 0 ? bq : (which == 1 ? bk : bv))[l*128 + so];
        (which == 0 ? bqp : (which == 1 ? bkp : bvp))[l*128 + o] = v;
    }
}

// ---------------------------------------------------------------------------
__global__ __launch_bounds__(256) void repack_xh_kernel(
    const float* __restrict__ in, u16* __restrict__ ohi, u16* __restrict__ olo)
{
    __shared__ float tile[32][68];
    int z = blockIdx.y >> 2, cg = blockIdx.y & 3;
    int n0 = blockIdx.x * 64;
    int t = threadIdx.x;
    {
        int i = t >> 3, nc = (t & 7) * 8;
        const float* src = &in[((size_t)z*128 + cg*32 + i)*NN + n0 + nc];
        float4 a = *(const float4*)src;
        float4 b = *(const float4*)(src + 4);
        tile[i][nc+0]=a.x; tile[i][nc+1]=a.y; tile[i][nc+2]=a.z; tile[i][nc+3]=a.w;
        tile[i][nc+4]=b.x; tile[i][nc+5]=b.y; tile[i][nc+6]=b.z; tile[i][nc+7]=b.w;
    }
    __syncthreads();
    int n = t >> 2, c8 = (t & 3) * 8;
    short8 hi, lo;
    #pragma unroll
    for (int j = 0; j < 8; ++j) {
        float v = tile[c8 + j][n];
        u16 h = f2bf(v);
        hi[j] = (short)h;
        lo[j] = (short)f2bf(v - bf2f(h));
    }
    size_t ob = ((size_t)z*NN + n0 + n)*128 + cg*32 + c8;
    *(short8*)&ohi[ob] = hi;
    *(short8*)&olo[ob] = lo;
}

// ---------------------------------------------------------------------------
// 64x64 GEMM core for a 256-thread sub-block (tt = sub-thread id).
// ---------------------------------------------------------------------------
__device__ __forceinline__ void gcore(
    u16* As0, u16* As1, u16* Bs0, u16* Bs1,
    const u16* Whi, const u16* Wlo, int o0, int Cin,
    const u16* B1hi, const u16* B1lo, int s1,
    const u16* B2hi, const u16* B2lo, int s2, int split,
    size_t brow, int n0, const int* idxp, int tt, f32x4 acc[2][2])
{
    const int lane = tt & 63, w = tt >> 6;
    const int l15 = lane & 15, quad = lane >> 4;
    const int wr = (w & 1)*32, wc = (w >> 1)*32;
    const int ao = tt >> 2, ak = (tt & 3)*8;
    int grow = n0 + ao;
    if (idxp) grow = idxp[grow];
    for (int kc = 0; kc < Cin; kc += 32) {
        {
            size_t wa = (size_t)(o0 + ao)*Cin + kc + ak;
            *(short8*)&As0[ao*40 + ak] = *(const short8*)&Whi[wa];
            *(short8*)&As1[ao*40 + ak] = *(const short8*)&Wlo[wa];
        }
        {
            int c = kc + ak;
            const u16 *ph, *pl;
            size_t off;
            if (c < split) { ph = B1hi; pl = B1lo; off = (brow + grow)*s1 + c; }
            else { ph = B2hi; pl = B2lo; off = (brow + grow)*s2 + (c - split); }
            *(short8*)&Bs0[ao*40 + ak] = *(const short8*)&ph[off];
            *(short8*)&Bs1[ao*40 + ak] = *(const short8*)&pl[off];
        }
        __syncthreads();
        short8 Ah[2], Al[2], Bh[2], Bl[2];
        #pragma unroll
        for (int a = 0; a < 2; ++a) {
            Ah[a] = *(const short8*)&As0[(wr + a*16 + l15)*40 + quad*8];
            Al[a] = *(const short8*)&As1[(wr + a*16 + l15)*40 + quad*8];
        }
        #pragma unroll
        for (int c = 0; c < 2; ++c) {
            Bh[c] = *(const short8*)&Bs0[(wc + c*16 + l15)*40 + quad*8];
            Bl[c] = *(const short8*)&Bs1[(wc + c*16 + l15)*40 + quad*8];
        }
        #pragma unroll
        for (int a = 0; a < 2; ++a)
            #pragma unroll
            for (int c = 0; c < 2; ++c) {
                acc[a][c] = __builtin_amdgcn_mfma_f32_16x16x32_bf16(Ah[a], Bl[c], acc[a][c], 0,0,0);
                acc[a][c] = __builtin_amdgcn_mfma_f32_16x16x32_bf16(Al[a], Bh[c], acc[a][c], 0,0,0);
                acc[a][c] = __builtin_amdgcn_mfma_f32_16x16x32_bf16(Ah[a], Bh[c], acc[a][c], 0,0,0);
            }
        __syncthreads();
    }
}

// ---------------------------------------------------------------------------
// The megakernel: all 4 layers, grid-barrier separated stages.
// ---------------------------------------------------------------------------
__global__ __launch_bounds__(512, 4) void mega_kernel(
    float* out, float* ws,
    const float* bm_all, const float* b1_all, const float* b2_all)
{
    __shared__ __align__(16) char smem[58880];

    const int blk = blockIdx.x;
    const int t = threadIdx.x;
    const int tt = t & 255, half = t >> 8;
    char* sbase = smem + half * 24576;

    // ---- workspace pointer table (matches round 8) ----
    const size_t U = 1048576;
    u16* ub   = (u16*)ws;
    u16* xphi = ub;            u16* xplo = ub + U;
    u16* qthi = ub + 2*U;      u16* qtlo = ub + 3*U;
    u16* kthi = ub + 4*U;      u16* ktlo = ub + 5*U;
    u16* vthi = ub + 6*U;
    u16* msghi = ub + 7*U;     u16* msglo = ub + 8*U;
    u16* m2hi = ub + 9*U;      u16* m2lo = ub + 10*U;
    u16* hhi  = ub + 11*U;     u16* hlo = ub + 13*U;
    u16* whi  = ub + 15*U;     u16* wlo = whi + 655360;
    float* zf = (float*)(ub + 2*U);
    float* ft = (float*)(wlo + 655360);
    float* bqp = ft;           float* bkp = ft + 512;    float* bvp = ft + 1024;
    float* gsum = ft + 1536;   float* gsq = ft + 2560;
    float* p = ft + 3584;
    int* idx0 = (int*)(p + 4*NN);
    int* idx1 = idx0 + NB*NN;
    int* rankb = idx1 + NB*NN;
    unsigned* cnt = (unsigned*)(rankb + 4*NN);
    unsigned* gen = cnt + 1;

    int g = 0;

    for (int l = 0; l < 4; ++l) {
        const int M = NN >> l;
        const int k_new = (M/2 < 128) ? 128 : M/2;
        const int cross = l & 1;
        const u16* Wlh = whi + (size_t)l*163840;
        const u16* Wll = wlo + (size_t)l*163840;
        const float* bqpl = bqp + l*128;
        const float* bkpl = bkp + l*128;
        const float* bvpl = bvp + l*128;
        const float* bm = bm_all + l*128;
        const float* b1 = b1_all + l*256;
        const float* b2 = b2_all + l*128;

        // ================= stage: QKV =================
        {
            int nsub = 256 + (M >> 2);
            if (2*blk < nsub) {
                int s = 2*blk + half;
                int role, o0, n0, nCols, z, bx = 0;
                const u16 *Wbh, *Wbl;
                const float* bias;
                if (s < 256) {
                    z = s >> 6; bx = s & 63;
                    role = 0; o0 = (bx & 1)*64; n0 = (bx >> 1)*64; nCols = NN;
                    Wbh = Wlh; Wbl = Wll; bias = bqpl;
                    if (tt < 32) p[(size_t)z*NN + bx*32 + tt] = 0.f;
                    if (bx == 0) gsum[z*256 + tt] = 0.f;
                    if (bx == 1) gsq[z*256 + tt] = 0.f;
                } else {
                    int e2 = s - 256;
                    int per_z = M >> 4;          // 4*(M/64)
                    z = e2 / per_z;
                    int rem = e2 % per_z;
                    int kt = M >> 6;
                    int rt = rem / kt, ct = rem % kt;
                    n0 = ct*64; nCols = M;
                    if (rt < 2) { role = 1; o0 = rt*64; Wbh = Wlh+16384; Wbl = Wll+16384; bias = bkpl; }
                    else        { role = 2; o0 = (rt-2)*64; Wbh = Wlh+32768; Wbl = Wll+32768; bias = bvpl; }
                }
                size_t brow = (size_t)z * NN;
                const int* idxp = nullptr;
                if (role != 0) {
                    int ss = cross ? 1 - (z >> 1) : (z >> 1);
                    brow = (size_t)(ss*2 + (z & 1)) * NN;
                    idxp = (ss ? idx1 : idx0) + (z & 1)*NN;
                }
                u16* As0 = (u16*)sbase;        u16* As1 = As0 + 2560;
                u16* Bs0 = As0 + 5120;         u16* Bs1 = As0 + 7680;
                f32x4 acc[2][2];
                #pragma unroll
                for (int a = 0; a < 2; ++a)
                    #pragma unroll
                    for (int c = 0; c < 2; ++c) acc[a][c] = (f32x4){0.f,0.f,0.f,0.f};
                gcore(As0, As1, Bs0, Bs1, Wbh, Wbl, o0, 128,
                      xphi, xplo, 128, xphi, xplo, 128, 128, brow, n0, idxp, tt, acc);

                const int lane = tt & 63, w = tt >> 6;
                const int l15 = lane & 15, quad = lane >> 4;
                const int wr = (w & 1)*32, wc = (w >> 1)*32;
                if (role == 2) {
                    #pragma unroll
                    for (int a = 0; a < 2; ++a)
                        #pragma unroll
                        for (int c = 0; c < 2; ++c)
                            #pragma unroll
                            for (int r = 0; r < 4; ++r) {
                                int row = o0 + wr + a*16 + quad*4 + r;
                                int m = n0 + wc + c*16 + l15;
                                float v = acc[a][c][r] + bias[row];
                                vthi[((size_t)(z*4 + (row>>5))*32 + (row&31))*(size_t)M + m] = f2bf(v);
                            }
                } else {
                    float* tb = (float*)sbase;   // [64][66]
                    float scale = role ? 1.f : QK_SCALE;
                    #pragma unroll
                    for (int a = 0; a < 2; ++a)
                        #pragma unroll
                        for (int c = 0; c < 2; ++c)
                            #pragma unroll
                            for (int r = 0; r < 4; ++r) {
                                int rl = wr + a*16 + quad*4 + r;
                                tb[rl*66 + wc + c*16 + l15] = acc[a][c][r] + bias[o0 + rl];
                            }
                    __syncthreads();
                    u16* ohi = role ? kthi : qthi;
                    u16* olo = role ? ktlo : qtlo;
                    int n = tt >> 2, rb = (tt & 3)*16;
                    #pragma unroll
                    for (int g2 = 0; g2 < 2; ++g2) {
                        short8 hi, lo;
                        #pragma unroll
                        for (int j = 0; j < 8; ++j) {
                            float v = tb[(rb + g2*8 + j)*66 + n] * scale;
                            u16 hb = f2bf(v);
                            hi[j] = (short)hb;
                            lo[j] = (short)f2bf(v - bf2f(hb));
                        }
                        int rowg = o0 + rb + g2*8;
                        size_t ob = ((size_t)(z*4 + (rowg >> 5))*nCols + n0 + n)*32 + (rowg & 31);
                        *(short8*)&ohi[ob] = hi;
                        *(short8*)&olo[ob] = lo;
                    }
                }
            }
        }
        gbar(cnt, gen, ++g);

        // ================= stage: attention (full 512-thread block) =========
        {
            u16* kv  = (u16*)smem;                     // ks0|ks1|vs
            u16* ks0 = kv;
            u16* ks1 = kv + 5120;
            u16* vs  = kv + 10240;                     // stride 136
            u16* Pw  = (u16*)(smem + 29184);           // [64][146]
            float* pcol = (float*)(smem + 47872);
            float* redm = (float*)(smem + 56064);      // [4][64]
            float* redl = (float*)(smem + 57088);
            float* rowM = (float*)(smem + 58112);
            float* rowIV = (float*)(smem + 58368);
            float* obuf = (float*)kv;

            const int vb = blk;
            const int bx = vb & 31, h = (vb >> 5) & 3, z = vb >> 7;
            const int zh = z*4 + h;
            const int n0 = bx * 64;
            const int lane = t & 63, wave = t >> 6;
            const int l15 = lane & 15, quad = lane >> 4;
            const int qp = wave & 1, mh = wave >> 1;

            for (int i = t; i < M; i += 512) pcol[i] = 0.f;

            short8 qBh[2], qBl[2];
            #pragma unroll
            for (int qt = 0; qt < 2; ++qt) {
                size_t qb = ((size_t)zh*NN + n0 + qp*32 + qt*16 + l15)*32 + quad*8;
                qBh[qt] = *(const short8*)&qthi[qb];
                qBl[qt] = *(const short8*)&qtlo[qb];
            }

            const int nch = M >> 7;
            const int sr = t >> 2, sc8 = (t & 3)*8;
            const int vr = t >> 4, vc8 = (t & 15)*8;

            float rm[2] = {-1e30f, -1e30f}, rl[2] = {0.f, 0.f};

            for (int ch = 0; ch < nch; ++ch) {
                const int m0 = ch << 7;
                {
                    size_t gk = ((size_t)zh*M + m0 + sr)*32 + sc8;
                    *(short8*)&ks0[sr*40 + sc8] = *(const short8*)&kthi[gk];
                    *(short8*)&ks1[sr*40 + sc8] = *(const short8*)&ktlo[gk];
                }
                __syncthreads();
                #pragma unroll
                for (int qt = 0; qt < 2; ++qt)
                    #pragma unroll
                    for (int mt = 0; mt < 2; ++mt) {
                        int mrow = mh*32 + mt*16 + l15;
                        short8 kh = *(const short8*)&ks0[mrow*40 + quad*8];
                        short8 kl = *(const short8*)&ks1[mrow*40 + quad*8];
                        f32x4 a = {0.f,0.f,0.f,0.f};
                        a = __builtin_amdgcn_mfma_f32_16x16x32_bf16(kh, qBl[qt], a, 0,0,0);
                        a = __builtin_amdgcn_mfma_f32_16x16x32_bf16(kl, qBh[qt], a, 0,0,0);
                        a = __builtin_amdgcn_mfma_f32_16x16x32_bf16(kh, qBh[qt], a, 0,0,0);
                        float bm2 = fmaxf(fmaxf(a[0],a[1]), fmaxf(a[2],a[3]));
                        float bs = __expf(a[0]-bm2)+__expf(a[1]-bm2)+__expf(a[2]-bm2)+__expf(a[3]-bm2);
                        if (bm2 > rm[qt]) { rl[qt] = rl[qt]*__expf(rm[qt]-bm2) + bs; rm[qt] = bm2; }
                        else rl[qt] += bs*__expf(bm2 - rm[qt]);
                    }
                __syncthreads();
            }

            #pragma unroll
            for (int qt = 0; qt < 2; ++qt) {
                #pragma unroll
                for (int off = 16; off <= 32; off <<= 1) {
                    float om = __shfl_xor(rm[qt], off);
                    float ol = __shfl_xor(rl[qt], off);
                    float nm = fmaxf(rm[qt], om);
                    rl[qt] = rl[qt]*__expf(rm[qt]-nm) + ol*__expf(om-nm);
                    rm[qt] = nm;
                }
                if (quad == 0) {
                    redm[mh*64 + qp*32 + qt*16 + l15] = rm[qt];
                    redl[mh*64 + qp*32 + qt*16 + l15] = rl[qt];
                }
            }
            __syncthreads();
            if (t < 64) {
                float m = redm[t], lsum = redl[t];
                #pragma unroll
                for (int w2 = 1; w2 < 4; ++w2) {
                    float om = redm[w2*64 + t];
                    float nm = fmaxf(m, om);
                    lsum = lsum*__expf(m - nm) + redl[w2*64 + t]*__expf(om - nm);
                    m = nm;
                }
                rowM[t] = m;
                rowIV[t] = 1.f / lsum;
            }
            __syncthreads();
            float myRM[2], myRIV[2];
            #pragma unroll
            for (int qt = 0; qt < 2; ++qt) {
                myRM[qt]  = rowM[qp*32 + qt*16 + l15];
                myRIV[qt] = rowIV[qp*32 + qt*16 + l15];
            }

            f32x4 oa[2][2];
            #pragma unroll
            for (int qt = 0; qt < 2; ++qt)
                #pragma unroll
                for (int dt = 0; dt < 2; ++dt) oa[qt][dt] = (f32x4){0.f,0.f,0.f,0.f};

            for (int ch = 0; ch < nch; ++ch) {
                const int m0 = ch << 7;
                {
                    size_t gk = ((size_t)zh*M + m0 + sr)*32 + sc8;
                    *(short8*)&ks0[sr*40 + sc8] = *(const short8*)&kthi[gk];
                    *(short8*)&ks1[sr*40 + sc8] = *(const short8*)&ktlo[gk];
                    *(short8*)&vs[vr*136 + vc8] =
                        *(const short8*)&vthi[((size_t)zh*32 + vr)*M + m0 + vc8];
                }
                __syncthreads();

                float pr[2][2][4];
                #pragma unroll
                for (int qt = 0; qt < 2; ++qt)
                    #pragma unroll
                    for (int mt = 0; mt < 2; ++mt) {
                        int mrow = mh*32 + mt*16 + l15;
                        short8 kh = *(const short8*)&ks0[mrow*40 + quad*8];
                        short8 kl = *(const short8*)&ks1[mrow*40 + quad*8];
                        f32x4 a = {0.f,0.f,0.f,0.f};
                        a = __builtin_amdgcn_mfma_f32_16x16x32_bf16(kh, qBl[qt], a, 0,0,0);
                        a = __builtin_amdgcn_mfma_f32_16x16x32_bf16(kl, qBh[qt], a, 0,0,0);
                        a = __builtin_amdgcn_mfma_f32_16x16x32_bf16(kh, qBh[qt], a, 0,0,0);
                        #pragma unroll
                        for (int r = 0; r < 4; ++r)
                            pr[qt][mt][r] = __expf(a[r] - myRM[qt]) * myRIV[qt];
                    }

                #pragma unroll
                for (int mt = 0; mt < 2; ++mt)
                    #pragma unroll
                    for (int r = 0; r < 4; ++r) {
                        float ps = pr[0][mt][r] + pr[1][mt][r];
                        ps += __shfl_xor(ps, 1);
                        ps += __shfl_xor(ps, 2);
                        ps += __shfl_xor(ps, 4);
                        ps += __shfl_xor(ps, 8);
                        if (l15 == 0)
                            atomicAdd(&pcol[m0 + mh*32 + mt*16 + quad*4 + r], ps);
                    }

                #pragma unroll
                for (int qt = 0; qt < 2; ++qt) {
                    int qrow = qp*32 + qt*16 + l15;
                    #pragma unroll
                    for (int mt = 0; mt < 2; ++mt) {
                        u16 h0 = f2bf(pr[qt][mt][0]), h1 = f2bf(pr[qt][mt][1]);
                        u16 h2 = f2bf(pr[qt][mt][2]), h3 = f2bf(pr[qt][mt][3]);
                        uint2 hv;
                        hv.x = (unsigned)h0 | ((unsigned)h1 << 16);
                        hv.y = (unsigned)h2 | ((unsigned)h3 << 16);
                        *(uint2*)&Pw[qrow*146 + mh*36 + mt*16 + quad*4] = hv;
                    }
                }

                #pragma unroll
                for (int qt = 0; qt < 2; ++qt) {
                    int qrow = qp*32 + qt*16 + l15;
                    short8 pAh = *(const short8*)&Pw[qrow*146 + mh*36 + quad*8];
                    #pragma unroll
                    for (int dt = 0; dt < 2; ++dt) {
                        short8 vh = *(const short8*)&vs[(dt*16 + l15)*136 + mh*32 + quad*8];
                        oa[qt][dt] = __builtin_amdgcn_mfma_f32_16x16x32_bf16(pAh, vh, oa[qt][dt], 0,0,0);
                    }
                }
                __syncthreads();
            }

            if (mh > 0) {
                #pragma unroll
                for (int qt = 0; qt < 2; ++qt)
                    #pragma unroll
                    for (int dt = 0; dt < 2; ++dt)
                        #pragma unroll
                        for (int r = 0; r < 4; ++r) {
                            int q = qp*32 + qt*16 + quad*4 + r;
                            obuf[((mh-1)*64 + q)*32 + dt*16 + l15] = oa[qt][dt][r];
                        }
            }
            __syncthreads();
            if (mh == 0) {
                #pragma unroll
                for (int qt = 0; qt < 2; ++qt)
                    #pragma unroll
                    for (int dt = 0; dt < 2; ++dt)
                        #pragma unroll
                        for (int r = 0; r < 4; ++r) {
                            int q = qp*32 + qt*16 + quad*4 + r;
                            float v = oa[qt][dt][r];
                            #pragma unroll
                            for (int w2 = 0; w2 < 3; ++w2)
                                v += obuf[(w2*64 + q)*32 + dt*16 + l15];
                            obuf[q*32 + dt*16 + l15] = v;
                        }
            }
            __syncthreads();
            {
                int tt2 = t & 255;
                int n = tt2 >> 2, i8 = (tt2 & 3)*8;
                short8 o8;
                if (t < 256) {
                    #pragma unroll
                    for (int j = 0; j < 8; ++j) o8[j] = (short)f2bf(obuf[n*32 + i8 + j]);
                    *(short8*)&msghi[((size_t)z*NN + n0 + n)*128 + h*32 + i8] = o8;
                } else {
                    #pragma unroll
                    for (int j = 0; j < 8; ++j) {
                        float v = obuf[n*32 + i8 + j];
                        u16 hb = f2bf(v);
                        o8[j] = (short)f2bf(v - bf2f(hb));
                    }
                    *(short8*)&msglo[((size_t)z*NN + n0 + n)*128 + h*32 + i8] = o8;
                }
            }
            for (int i = t; i < M; i += 512)
                atomicAdd(&p[(size_t)z*NN + i], pcol[i]*0.25f);
        }
        gbar(cnt, gen, ++g);

        // ================= stage: Wm GEMM + rank =================
        {
            int nsub = 256 + ((M >> 8) << 2);
            if (2*blk < nsub) {
                int s = 2*blk + half;
                if (s < 256) {
                    int z = s >> 6, rem = s & 63;
                    int o0 = (rem >> 5)*64, n0 = (rem & 31)*64;
                    u16* As0 = (u16*)sbase;  u16* As1 = As0 + 2560;
                    u16* Bs0 = As0 + 5120;   u16* Bs1 = As0 + 7680;
                    f32x4 acc[2][2];
                    #pragma unroll
                    for (int a = 0; a < 2; ++a)
                        #pragma unroll
                        for (int c = 0; c < 2; ++c) acc[a][c] = (f32x4){0.f,0.f,0.f,0.f};
                    gcore(As0, As1, Bs0, Bs1, Wlh + 49152, Wll + 49152, o0, 128,
                          msghi, msglo, 128, msghi, msglo, 128, 128,
                          (size_t)z*NN, n0, nullptr, tt, acc);
                    const int lane = tt & 63, w = tt >> 6;
                    const int l15 = lane & 15, quad = lane >> 4;
                    const int wr = (w & 1)*32, wc = (w >> 1)*32;
                    float* tb = (float*)sbase;
                    #pragma unroll
                    for (int a = 0; a < 2; ++a)
                        #pragma unroll
                        for (int c = 0; c < 2; ++c)
                            #pragma unroll
                            for (int r = 0; r < 4; ++r) {
                                int rl2 = wr + a*16 + quad*4 + r;
                                tb[rl2*66 + wc + c*16 + l15] = acc[a][c][r] + bm[o0 + rl2];
                            }
                    __syncthreads();
                    int n = tt >> 2, rb = (tt & 3)*16;
                    #pragma unroll
                    for (int g2 = 0; g2 < 2; ++g2) {
                        short8 hi, lo;
                        #pragma unroll
                        for (int j = 0; j < 8; ++j) {
                            float v = tb[(rb + g2*8 + j)*66 + n];
                            u16 hb = f2bf(v);
                            hi[j] = (short)hb;
                            lo[j] = (short)f2bf(v - bf2f(hb));
                        }
                        size_t ob = ((size_t)z*NN + n0 + n)*128 + o0 + rb + g2*8;
                        *(short8*)&m2hi[ob] = hi;
                        *(short8*)&m2lo[ob] = lo;
                    }
                } else {
                    int e = s - 256;
                    int nbz = M >> 8;
                    int zz = e / nbz, bxx = e % nbz;
                    float* pv = (float*)sbase;
                    for (int i = tt; i < M; i += 256) pv[i] = p[(size_t)zz*NN + i];
                    __syncthreads();
                    int i = bxx*256 + tt;
                    float pi = pv[i];
                    int r = 0;
                    for (int j = 0; j < M; ++j) {
                        float pj = pv[j];
                        r += (pj > pi) ? 1 : ((pj == pi && j < i) ? 1 : 0);
                    }
                    rankb[zz*NN + i] = r;
                }
            }
        }
        gbar(cnt, gen, ++g);

        // ================= stage: W1 GEMM + select =================
        {
            if (blk < 256) {
                int s = 2*blk + half;
                int z = s >> 7, rem = s & 127;
                int o0 = (rem >> 5)*64, n0 = (rem & 31)*64;
                u16* As0 = (u16*)sbase;  u16* As1 = As0 + 2560;
                u16* Bs0 = As0 + 5120;   u16* Bs1 = As0 + 7680;
                f32x4 acc[2][2];
                #pragma unroll
                for (int a = 0; a < 2; ++a)
                    #pragma unroll
                    for (int c = 0; c < 2; ++c) acc[a][c] = (f32x4){0.f,0.f,0.f,0.f};
                gcore(As0, As1, Bs0, Bs1, Wlh + 65536, Wll + 65536, o0, 256,
                      xphi, xplo, 128, m2hi, m2lo, 128, 128,
                      (size_t)z*NN, n0, nullptr, tt, acc);
                const int lane = tt & 63, w = tt >> 6;
                const int l15 = lane & 15, quad = lane >> 4;
                const int wr = (w & 1)*32, wc = (w >> 1)*32;
                float ssum[2][4], ssq[2][4];
                #pragma unroll
                for (int a = 0; a < 2; ++a)
                    #pragma unroll
                    for (int r = 0; r < 4; ++r) { ssum[a][r] = 0.f; ssq[a][r] = 0.f; }
                #pragma unroll
                for (int a = 0; a < 2; ++a)
                    #pragma unroll
                    for (int c = 0; c < 2; ++c)
                        #pragma unroll
                        for (int r = 0; r < 4; ++r) {
                            int row = o0 + wr + a*16 + quad*4 + r;
                            int n = n0 + wc + c*16 + l15;
                            float v = acc[a][c][r] + b1[row];
                            zf[((size_t)z*256 + row)*NN + n] = v;
                            ssum[a][r] += v;
                            ssq[a][r] = fmaf(v, v, ssq[a][r]);
                        }
                #pragma unroll
                for (int a = 0; a < 2; ++a)
                    #pragma unroll
                    for (int r = 0; r < 4; ++r) {
                        float sv = ssum[a][r], q2 = ssq[a][r];
                        #pragma unroll
                        for (int o = 1; o < 16; o <<= 1) {
                            sv += __shfl_xor(sv, o);
                            q2 += __shfl_xor(q2, o);
                        }
                        if (l15 == 0) {
                            int row = o0 + wr + a*16 + quad*4 + r;
                            atomicAdd(&gsum[z*256 + row], sv);
                            atomicAdd(&gsq[z*256 + row], q2);
                        }
                    }
            } else if (blk < 260) {
                int z = blk - 256;
                int* sel = (int*)smem;
                int* idv = sel + 2048;
                int* sa = idv + 2048;
                int* sb2 = sa + 2048;
                int st = z >> 1, b = z & 1;
                int ts = cross ? 1 - st : st;
                int* idx = (ts ? idx1 : idx0) + b*NN;
                const int* rk = rankb + z*NN;
                for (int i = t; i < M; i += 512) {
                    int s2 = rk[i] < k_new ? 1 : 0;
                    sel[i] = s2;
                    sa[i] = s2;
                    idv[i] = idx[i];
                }
                __syncthreads();
                int* src = sa; int* dst = sb2;
                for (int off = 1; off < M; off <<= 1) {
                    for (int i = t; i < M; i += 512)
                        dst[i] = src[i] + (i >= off ? src[i - off] : 0);
                    __syncthreads();
                    int* tmp = src; src = dst; dst = tmp;
                }
                for (int i = t; i < M; i += 512)
                    if (sel[i]) idx[src[i] - 1] = idv[i];
            }
        }
        gbar(cnt, gen, ++g);

        // ================= stage: hrepack =================
        {
            int s = 2*blk + half;          // 1024 subs, all blocks active
            int by = s >> 5, bxx = s & 31;
            int z = by >> 3, cg = by & 7;
            int n0 = bxx * 64;
            float* tile = (float*)sbase;   // [32][68]
            {
                int i = tt >> 3, nc = (tt & 7) * 8;
                int c = cg*32 + i;
                float mean = gsum[z*256 + c] * (1.f/NN);
                float var = gsq[z*256 + c] * (1.f/NN) - mean*mean;
                float iv = rsqrtf(var + IN_EPS);
                const float* src = &zf[((size_t)z*256 + c)*NN + n0 + nc];
                float4 a = *(const float4*)src;
                float4 b = *(const float4*)(src + 4);
                float vv[8] = {a.x,a.y,a.z,a.w,b.x,b.y,b.z,b.w};
                #pragma unroll
                for (int j = 0; j < 8; ++j) {
                    float v = (vv[j] - mean) * iv;
                    tile[(i)*68 + nc + j] = v > 0.f ? v : 0.f;
                }
            }
            __syncthreads();
            int n = tt >> 2, c8 = (tt & 3) * 8;
            short8 hi, lo;
            #pragma unroll
            for (int j = 0; j < 8; ++j) {
                float v = tile[(c8 + j)*68 + n];
                u16 hb = f2bf(v);
                hi[j] = (short)hb;
                lo[j] = (short)f2bf(v - bf2f(hb));
            }
            size_t ob = ((size_t)z*NN + n0 + n)*256 + cg*32 + c8;
            *(short8*)&hhi[ob] = hi;
            *(short8*)&hlo[ob] = lo;
        }
        gbar(cnt, gen, ++g);

        // ================= stage: W2 GEMM =================
        {
            if (blk < 128) {
                int s = 2*blk + half;
                int z = s >> 6, rem = s & 63;
                int o0 = (rem >> 5)*64, n0 = (rem & 31)*64;
                u16* As0 = (u16*)sbase;  u16* As1 = As0 + 2560;
                u16* Bs0 = As0 + 5120;   u16* Bs1 = As0 + 7680;
                f32x4 acc[2][2];
                #pragma unroll
                for (int a = 0; a < 2; ++a)
                    #pragma unroll
                    for (int c = 0; c < 2; ++c) acc[a][c] = (f32x4){0.f,0.f,0.f,0.f};
                gcore(As0, As1, Bs0, Bs1, Wlh + 131072, Wll + 131072, o0, 256,
                      hhi, hlo, 256, hhi, hlo, 256, 256,
                      (size_t)z*NN, n0, nullptr, tt, acc);
                const int lane = tt & 63, w = tt >> 6;
                const int l15 = lane & 15, quad = lane >> 4;
                const int wr = (w & 1)*32, wc = (w >> 1)*32;
                float* tb = (float*)sbase;
                #pragma unroll
                for (int a = 0; a < 2; ++a)
                    #pragma unroll
                    for (int c = 0; c < 2; ++c)
                        #pragma unroll
                        for (int r = 0; r < 4; ++r) {
                            int rl2 = wr + a*16 + quad*4 + r;
                            int rowg = o0 + rl2;
                            int n = n0 + wc + c*16 + l15;
                            size_t oi = ((size_t)z*128 + rowg)*NN + n;
                            float v = acc[a][c][r] + b2[rowg] + out[oi];
                            out[oi] = v;
                            tb[rl2*66 + wc + c*16 + l15] = v;
                        }
                __syncthreads();
                if (l < 3) {
                    int n = tt >> 2, rb = (tt & 3)*16;
                    #pragma unroll
                    for (int g2 = 0; g2 < 2; ++g2) {
                        short8 hi, lo;
                        #pragma unroll
                        for (int j = 0; j < 8; ++j) {
                            float v = tb[(rb + g2*8 + j)*66 + n];
                            u16 hb = f2bf(v);
                            hi[j] = (short)hb;
                            lo[j] = (short)f2bf(v - bf2f(hb));
                        }
                        size_t ob = ((size_t)z*NN + n0 + n)*128 + o0 + rb + g2*8;
                        *(short8*)&xphi[ob] = hi;
                        *(short8*)&xplo[ob] = lo;
                    }
                }
            }
        }
        gbar(cnt, gen, ++g);
    }
}

// ---------------------------------------------------------------------------
extern "C" void kernel_launch(void* const* d_in, const int* in_sizes, int n_in,
                              void* d_out, int out_size, void* d_ws, size_t ws_size,
                              hipStream_t stream)
{
    const float* x0in = (const float*)d_in[0];
    const float* x1in = (const float*)d_in[1];
    const float* Wq = (const float*)d_in[2];
    const float* bq = (const float*)d_in[3];
    const float* Wk = (const float*)d_in[4];
    const float* bk = (const float*)d_in[5];
    const float* Wv = (const float*)d_in[6];
    const float* bv = (const float*)d_in[7];
    const float* Wm = (const float*)d_in[8];
    const float* bm = (const float*)d_in[9];
    const float* W1 = (const float*)d_in[10];
    const float* b1 = (const float*)d_in[11];
    const float* W2 = (const float*)d_in[12];
    const float* b2 = (const float*)d_in[13];

    float* out = (float*)d_out;
    float* ws  = (float*)d_ws;

    const size_t U = 1048576;
    u16* ub   = (u16*)ws;
    u16* xphi = ub;            u16* xplo = ub + U;
    u16* whi  = ub + 15*U;     u16* wlo = whi + 655360;
    float* ft = (float*)(wlo + 655360);
    float* bqp = ft;           float* bkp = ft + 512;    float* bvp = ft + 1024;
    float* p = ft + 3584;
    int* idx0 = (int*)(p + 4*NN);
    int* idx1 = idx0 + NB*NN;
    int* rankb = idx1 + NB*NN;
    unsigned* cnt = (unsigned*)(rankb + 4*NN);
    unsigned* gen = cnt + 1;

    barinit_kernel<<<1, 64, 0, stream>>>(cnt, gen);
    init_kernel<<<BDN/4/256, 256, 0, stream>>>(x0in, x1in, out, idx0, idx1);
    wrepack2_kernel<<<2566, 256, 0, stream>>>(Wq, Wk, Wv, Wm, W1, W2, bq, bk, bv,
                                              whi, wlo, bqp, bkp, bvp);
    repack_xh_kernel<<<dim3(32, 16), 256, 0, stream>>>(out, xphi, xplo);

    mega_kernel<<<NBLK, 512, 0, stream>>>(out, ws, bm, b1, b2);
}